// Round 1
// baseline (72.317 us; speedup 1.0000x reference)
//
#include <hip/hip_runtime.h>
#include <hip/hip_bf16.h>

// EquivariantLayerNorm: irreps = 128x0e + 64x1o + 32x2e, DIM=480, 224 instances.
// One wave (64 lanes) per row. Lane i owns:
//   scalars 2i,2i+1          (0e, d=1)  -> float2 load at   [2i]
//   1o instance i            (d=3)      -> 3 floats at      [128+3i]
//   2e instance i (lane<32)  (d=5)      -> 5 floats at      [320+5i]
// Two wave reductions (scalar mean, sum of norm^2). fp32 throughout.

#define NROW_TOTAL_DIM 480
#define ROWS_PER_BLOCK 4

__global__ __launch_bounds__(256) void eln_kernel(
    const float* __restrict__ in,     // [n, 480]
    const float* __restrict__ wgt,    // [224]
    const float* __restrict__ bias,   // [128]
    float* __restrict__ out,          // [n, 480]
    int n_rows)
{
    const int wave = threadIdx.x >> 6;
    const int lane = threadIdx.x & 63;
    const int row  = blockIdx.x * ROWS_PER_BLOCK + wave;
    if (row >= n_rows) return;

    const float* x = in  + (size_t)row * NROW_TOTAL_DIM;
    float*       y = out + (size_t)row * NROW_TOTAL_DIM;

    // ---- loads ----
    float2 s = *reinterpret_cast<const float2*>(x + 2 * lane);   // scalars

    const float* p1 = x + 128 + 3 * lane;                        // 1o instance
    float v0 = p1[0], v1 = p1[1], v2 = p1[2];

    float e0 = 0.f, e1 = 0.f, e2 = 0.f, e3 = 0.f, e4 = 0.f;      // 2e instance
    if (lane < 32) {
        const float* p2 = x + 320 + 5 * lane;
        e0 = p2[0]; e1 = p2[1]; e2 = p2[2]; e3 = p2[3]; e4 = p2[4];
    }

    // ---- scalar mean over 128 channels ----
    float ssum = s.x + s.y;
    #pragma unroll
    for (int m = 1; m < 64; m <<= 1) ssum += __shfl_xor(ssum, m);
    const float mean = ssum * (1.0f / 128.0f);
    s.x -= mean;
    s.y -= mean;

    // ---- per-instance norms: sqrt(sum((x+eps^2)^2)) - eps,  eps = 1e-6 ----
    const float epsq = 1e-12f;   // eps^2
    const float eps  = 1e-6f;

    float n0 = fabsf(s.x + epsq) - eps;          // d=1: sqrt((x+e)^2) = |x+e|
    float n1 = fabsf(s.y + epsq) - eps;

    float a0 = v0 + epsq, a1 = v1 + epsq, a2 = v2 + epsq;
    float n2 = sqrtf(a0 * a0 + a1 * a1 + a2 * a2) - eps;

    float nsq = n0 * n0 + n1 * n1 + n2 * n2;

    if (lane < 32) {
        float b0 = e0 + epsq, b1 = e1 + epsq, b2 = e2 + epsq,
              b3 = e3 + epsq, b4 = e4 + epsq;
        float n3 = sqrtf(b0 * b0 + b1 * b1 + b2 * b2 + b3 * b3 + b4 * b4) - eps;
        nsq += n3 * n3;
    }

    // ---- RMS over 224 instances ----
    #pragma unroll
    for (int m = 1; m < 64; m <<= 1) nsq += __shfl_xor(nsq, m);
    const float inv_rms = rsqrtf(nsq * (1.0f / 224.0f));

    // ---- affine + bias, store ----
    {
        float w0 = wgt[2 * lane], w1 = wgt[2 * lane + 1];
        float2 so;
        so.x = s.x * inv_rms * w0 + bias[2 * lane];
        so.y = s.y * inv_rms * w1 + bias[2 * lane + 1];
        *reinterpret_cast<float2*>(y + 2 * lane) = so;
    }
    {
        float wv = wgt[128 + lane] * inv_rms;
        float* q1 = y + 128 + 3 * lane;
        q1[0] = v0 * wv;
        q1[1] = v1 * wv;
        q1[2] = v2 * wv;
    }
    if (lane < 32) {
        float we = wgt[192 + lane] * inv_rms;
        float* q2 = y + 320 + 5 * lane;
        q2[0] = e0 * we;
        q2[1] = e1 * we;
        q2[2] = e2 * we;
        q2[3] = e3 * we;
        q2[4] = e4 * we;
    }
}

extern "C" void kernel_launch(void* const* d_in, const int* in_sizes, int n_in,
                              void* d_out, int out_size, void* d_ws, size_t ws_size,
                              hipStream_t stream) {
    const float* node_input    = (const float*)d_in[0];
    const float* affine_weight = (const float*)d_in[1];
    const float* affine_bias   = (const float*)d_in[2];
    float* out = (float*)d_out;

    const int n_rows = in_sizes[0] / NROW_TOTAL_DIM;   // 100000
    const int grid = (n_rows + ROWS_PER_BLOCK - 1) / ROWS_PER_BLOCK;

    eln_kernel<<<grid, 256, 0, stream>>>(node_input, affine_weight, affine_bias,
                                         out, n_rows);
}